// Round 6
// baseline (377.750 us; speedup 1.0000x reference)
//
#include <hip/hip_runtime.h>

// CompositeValueNoise R6: 512-bucket global counting sort + fused in-LDS
// fine sort (64 sub-bins) in main. vs R5: (a) tmp written at fine-sorted
// position -> coalesced full-line stores; rank[orig]=finalpos written from
// main (4B scattered, LLC-merged); (b) XCD-compact bucket mapping: each XCD
// gets a 4x4x4 octant, enumerated so ~32 resident buckets form a 2x4x4
// block (concurrent grid slice ~2.5 MB < 4 MB L2).

#define NB 512                 // 8^3 coarse buckets
#define PTS_PER_BLK 4096
#define CHUNK 32
#define SC_THREADS 1024
#define SC_PPT (PTS_PER_BLK / SC_THREADS)
#define H_THREADS 256
#define H_PPT (PTS_PER_BLK / H_THREADS)
#define TILE 4608              // mean seg 3906, sd ~62 -> +11 sigma

__device__ __forceinline__ int bucket_of(float px, float py, float pz) {
    int ix = min(max((int)(px * 8.0f), 0), 7);
    int iy = min(max((int)(py * 8.0f), 0), 7);
    int iz = min(max((int)(pz * 8.0f), 0), 7);
    return (ix * 8 + iy) * 8 + iz;
}

__global__ void __launch_bounds__(H_THREADS)
cvn_hist(const float* __restrict__ x, int* __restrict__ P, int n) {
    __shared__ int cnt[NB];
    int t = threadIdx.x;
    for (int q = t; q < NB; q += H_THREADS) cnt[q] = 0;
    __syncthreads();
    int base = blockIdx.x * PTS_PER_BLK;
    for (int k = 0; k < H_PPT; ++k) {
        int i = base + k * H_THREADS + t;
        if (i < n)
            atomicAdd(&cnt[bucket_of(x[3 * i], x[3 * i + 1], x[3 * i + 2])], 1);
    }
    __syncthreads();
    int* Pb = P + (size_t)blockIdx.x * NB;
    for (int q = t; q < NB; q += H_THREADS) Pb[q] = cnt[q];
}

__global__ void __launch_bounds__(256)
cvn_scan_a(const int* __restrict__ P, int* __restrict__ S, int nblk) {
    int q = blockIdx.x * 256 + threadIdx.x;
    int c = blockIdx.y;
    int b0 = c * CHUNK, b1 = min(b0 + CHUNK, nblk);
    int s = 0;
    for (int b = b0; b < b1; ++b) s += P[(size_t)b * NB + q];
    S[(size_t)c * NB + q] = s;
}

// After: S[c][q] = Texcl[q] + exclusive chunk prefix; S[0][q] = bucket base.
__global__ void __launch_bounds__(NB)
cvn_scan_b(int* __restrict__ S, int nch) {
    __shared__ int part[NB];
    int t = threadIdx.x;
    int acc = 0;
    for (int c = 0; c < nch; ++c) {
        int v = S[(size_t)c * NB + t];
        S[(size_t)c * NB + t] = acc;
        acc += v;
    }
    part[t] = acc;
    __syncthreads();
    for (int off = 1; off < NB; off <<= 1) {
        int v = (t >= off) ? part[t - off] : 0;
        __syncthreads();
        if (t >= off) part[t] += v;
        __syncthreads();
    }
    int texcl = (t == 0) ? 0 : part[t - 1];
    for (int c = 0; c < nch; ++c) S[(size_t)c * NB + t] += texcl;
}

__global__ void __launch_bounds__(256)
cvn_scan_c(int* __restrict__ P, const int* __restrict__ S, int nblk) {
    int q = blockIdx.x * 256 + threadIdx.x;
    int c = blockIdx.y;
    int b0 = c * CHUNK, b1 = min(b0 + CHUNK, nblk);
    int run = S[(size_t)c * NB + q];
    for (int b = b0; b < b1; ++b) {
        int v = P[(size_t)b * NB + q];
        P[(size_t)b * NB + q] = run;
        run += v;
    }
}

__global__ void __launch_bounds__(SC_THREADS)
cvn_scatter(const float* __restrict__ x, const int* __restrict__ P,
            float4* __restrict__ sorted, int n) {
    __shared__ int cnt[NB];
    __shared__ int place[NB];
    __shared__ int Pb[NB];
    __shared__ int sc[NB];
    __shared__ float4 payload[PTS_PER_BLK];
    __shared__ unsigned short bkt[PTS_PER_BLK];
    int t = threadIdx.x, b = blockIdx.x;
    int base = b * PTS_PER_BLK;
    if (t < NB) {
        cnt[t] = 0; place[t] = 0;
        Pb[t] = P[(size_t)b * NB + t];
    }
    __syncthreads();

    float px[SC_PPT], py[SC_PPT], pz[SC_PPT];
    int qq[SC_PPT];
    #pragma unroll
    for (int k = 0; k < SC_PPT; ++k) {
        int i = base + k * SC_THREADS + t;
        if (i < n) {
            px[k] = x[3 * i]; py[k] = x[3 * i + 1]; pz[k] = x[3 * i + 2];
            qq[k] = bucket_of(px[k], py[k], pz[k]);
            atomicAdd(&cnt[qq[k]], 1);
        } else qq[k] = -1;
    }
    __syncthreads();

    if (t < NB) sc[t] = cnt[t];
    __syncthreads();
    for (int off = 1; off < NB; off <<= 1) {
        int v = (t < NB && t >= off) ? sc[t - off] : 0;
        __syncthreads();
        if (t < NB && t >= off) sc[t] += v;
        __syncthreads();
    }
    if (t < NB) cnt[t] = (t == 0) ? 0 : sc[t - 1];
    __syncthreads();

    #pragma unroll
    for (int k = 0; k < SC_PPT; ++k) {
        if (qq[k] >= 0) {
            int q = qq[k];
            int lp = atomicAdd(&place[q], 1);
            int slot = cnt[q] + lp;
            int i = base + k * SC_THREADS + t;
            payload[slot] = make_float4(px[k], py[k], pz[k], __int_as_float(i));
            bkt[slot] = (unsigned short)q;
        }
    }
    __syncthreads();

    int total = min(n - base, PTS_PER_BLK);
    #pragma unroll
    for (int k = 0; k < SC_PPT; ++k) {
        int j = k * SC_THREADS + t;
        if (j < total) {
            int q = bkt[j];
            sorted[Pb[q] + (j - cnt[q])] = payload[j];
        }
    }
}

__device__ __forceinline__ float4 lerp4(float4 a, float4 b, float w) {
    return make_float4(a.x + w * (b.x - a.x),
                       a.y + w * (b.y - a.y),
                       a.z + w * (b.z - a.z),
                       a.w + w * (b.w - a.w));
}

template <int RES>
__device__ __forceinline__ float4 level_val(const float4* __restrict__ V,
                                            float px, float py, float pz) {
    constexpr int S = RES + 1;
    float xs = fmodf(px * (float)RES, (float)RES);
    float ys = fmodf(py * (float)RES, (float)RES);
    float zs = fmodf(pz * (float)RES, (float)RES);
    float fx = floorf(xs), fy = floorf(ys), fz = floorf(zs);
    float tx = xs - fx, ty = ys - fy, tz = zs - fz;
    int ix = (int)fx, iy = (int)fy, iz = (int)fz;

    float wx = (3.0f - 2.0f * tx) * tx * tx;
    float wy = (3.0f - 2.0f * ty) * ty * ty;
    float wz = (3.0f - 2.0f * tz) * tz * tz;

    int base = (ix * S + iy) * S + iz;
    const float4* p0 = V + base;
    const float4* p1 = p0 + S * S;

    float4 c000 = p0[0];
    float4 c001 = p0[1];
    float4 c010 = p0[S];
    float4 c011 = p0[S + 1];
    float4 c100 = p1[0];
    float4 c101 = p1[1];
    float4 c110 = p1[S];
    float4 c111 = p1[S + 1];

    float4 m00 = lerp4(c000, c100, wx);
    float4 m01 = lerp4(c001, c101, wx);
    float4 m10 = lerp4(c010, c110, wx);
    float4 m11 = lerp4(c011, c111, wx);
    float4 n0  = lerp4(m00, m10, wy);
    float4 n1  = lerp4(m01, m11, wy);
    return lerp4(n0, n1, wz);
}

__device__ __forceinline__ float4 composite(const float4* __restrict__ V16,
                                            const float4* __restrict__ V32,
                                            const float4* __restrict__ V64,
                                            const float4* __restrict__ V128,
                                            float px, float py, float pz) {
    float4 acc = level_val<16>(V16, px, py, pz);
    float4 v;
    v = level_val<32>(V32, px, py, pz);
    acc.x += 0.5f * v.x; acc.y += 0.5f * v.y; acc.z += 0.5f * v.z; acc.w += 0.5f * v.w;
    v = level_val<64>(V64, px, py, pz);
    acc.x += 0.25f * v.x; acc.y += 0.25f * v.y; acc.z += 0.25f * v.z; acc.w += 0.25f * v.w;
    v = level_val<128>(V128, px, py, pz);
    acc.x += 0.125f * v.x; acc.y += 0.125f * v.y; acc.z += 0.125f * v.z; acc.w += 0.125f * v.w;
    return acc;
}

// One WG per coarse bucket, XCD-compact mapping; in-LDS fine sort (64 bins);
// coalesced tmp write at fine-sorted position; rank[orig] = final position.
__global__ void __launch_bounds__(1024)
cvn_main2(const float4* __restrict__ sorted, const int* __restrict__ Tbase,
          const float4* __restrict__ V16, const float4* __restrict__ V32,
          const float4* __restrict__ V64, const float4* __restrict__ V128,
          float4* __restrict__ tmp, int* __restrict__ rank, int n) {
    __shared__ float4 pts[TILE];
    __shared__ unsigned short keys[TILE];
    __shared__ unsigned short perm[TILE];
    __shared__ int bins[64];
    int t = threadIdx.x, b = blockIdx.x;

    // b&7 -> XCD -> octant (4x4x4 coarse cells); g enumerated x-slowest so
    // first ~32 resident g's per XCD form a compact 2x4x4 block.
    int ox = b & 1, oy = (b >> 1) & 1, oz = (b >> 2) & 1;
    int g  = b >> 3;                       // 0..63
    int lx = g >> 4, ly = (g >> 2) & 3, lz = g & 3;
    int ix = ox * 4 + lx, iy = oy * 4 + ly, iz = oz * 4 + lz;
    int q  = (ix * 8 + iy) * 8 + iz;

    int base = Tbase[q];
    int end  = (q == NB - 1) ? n : Tbase[q + 1];
    int len  = end - base;
    int lenT = min(len, TILE);

    if (t < 64) bins[t] = 0;
    __syncthreads();

    for (int p = t; p < lenT; p += 1024) {
        float4 pt = sorted[base + p];
        pts[p] = pt;
        int kx = min(max((int)(pt.x * 32.0f), 0), 31) & 3;
        int ky = min(max((int)(pt.y * 32.0f), 0), 31) & 3;
        int kz = min(max((int)(pt.z * 32.0f), 0), 31) & 3;
        int key = (kx * 4 + ky) * 4 + kz;
        keys[p] = (unsigned short)key;
        atomicAdd(&bins[key], 1);
    }
    __syncthreads();

    if (t == 0) {
        int s = 0;
        for (int k = 0; k < 64; ++k) { int c = bins[k]; bins[k] = s; s += c; }
    }
    __syncthreads();

    for (int p = t; p < lenT; p += 1024) {
        int slot = atomicAdd(&bins[keys[p]], 1);
        perm[slot] = (unsigned short)p;
    }
    __syncthreads();

    for (int p = t; p < lenT; p += 1024) {
        float4 pt = pts[perm[p]];
        tmp[base + p] = composite(V16, V32, V64, V128, pt.x, pt.y, pt.z);
        rank[__float_as_int(pt.w)] = base + p;
    }
    for (int p = lenT + t; p < len; p += 1024) {   // ~never
        float4 pt = sorted[base + p];
        tmp[base + p] = composite(V16, V32, V64, V128, pt.x, pt.y, pt.z);
        rank[__float_as_int(pt.w)] = base + p;
    }
}

// Mid-tier fallback: coarse-sorted order, scattered out write.
__global__ void __launch_bounds__(256)
cvn_main(const float4* __restrict__ sorted,
         const float4* __restrict__ V16, const float4* __restrict__ V32,
         const float4* __restrict__ V64, const float4* __restrict__ V128,
         float4* __restrict__ outbuf, int n, int nblocks) {
    int nb8 = nblocks >> 3;
    int c = (blockIdx.x & 7) * nb8 + (blockIdx.x >> 3);
    int j = c * 256 + (int)threadIdx.x;
    if (j >= n) return;
    float4 p = sorted[j];
    outbuf[__float_as_int(p.w)] = composite(V16, V32, V64, V128, p.x, p.y, p.z);
}

__global__ void __launch_bounds__(256)
cvn_permute(const float4* __restrict__ tmp, const int* __restrict__ rank,
            float4* __restrict__ out, int n) {
    int i = blockIdx.x * 256 + (int)threadIdx.x;
    if (i >= n) return;
    out[i] = tmp[rank[i]];
}

__global__ void __launch_bounds__(256)
cvn_direct(const float* __restrict__ x,
           const float4* __restrict__ V16, const float4* __restrict__ V32,
           const float4* __restrict__ V64, const float4* __restrict__ V128,
           float4* __restrict__ out, int n) {
    int i = blockIdx.x * blockDim.x + threadIdx.x;
    if (i >= n) return;
    out[i] = composite(V16, V32, V64, V128, x[3 * i], x[3 * i + 1], x[3 * i + 2]);
}

extern "C" void kernel_launch(void* const* d_in, const int* in_sizes, int n_in,
                              void* d_out, int out_size, void* d_ws, size_t ws_size,
                              hipStream_t stream) {
    const float*  x    = (const float*)d_in[0];
    const float4* V16  = (const float4*)d_in[1];
    const float4* V32  = (const float4*)d_in[2];
    const float4* V64  = (const float4*)d_in[3];
    const float4* V128 = (const float4*)d_in[4];
    float4* out = (float4*)d_out;

    int n = in_sizes[0] / 3;
    int nblk = (n + PTS_PER_BLK - 1) / PTS_PER_BLK;
    int nch  = (nblk + CHUNK - 1) / CHUNK;

    auto align256 = [](size_t v) { return (v + 255) & ~(size_t)255; };
    size_t offP      = 0;
    size_t offS      = align256(offP + (size_t)nblk * NB * sizeof(int));
    size_t offSorted = align256(offS + (size_t)nch * NB * sizeof(int));
    size_t offRank   = align256(offSorted + (size_t)n * sizeof(float4));
    size_t offTmp    = align256(offRank + (size_t)n * sizeof(int));
    size_t needFull  = offTmp + (size_t)n * sizeof(float4);
    size_t needMid   = offRank;

    int grid256 = (n + 255) / 256;
    int nblocks = ((grid256 + 7) / 8) * 8;

    if (ws_size >= needMid) {
        int*    P      = (int*)((char*)d_ws + offP);
        int*    S      = (int*)((char*)d_ws + offS);
        float4* sorted = (float4*)((char*)d_ws + offSorted);
        bool full = (ws_size >= needFull);
        int*    rank = full ? (int*)((char*)d_ws + offRank) : nullptr;
        float4* tmp  = full ? (float4*)((char*)d_ws + offTmp) : nullptr;

        cvn_hist<<<nblk, H_THREADS, 0, stream>>>(x, P, n);
        cvn_scan_a<<<dim3(NB / 256, nch), 256, 0, stream>>>(P, S, nblk);
        cvn_scan_b<<<1, NB, 0, stream>>>(S, nch);
        cvn_scan_c<<<dim3(NB / 256, nch), 256, 0, stream>>>(P, S, nblk);
        cvn_scatter<<<nblk, SC_THREADS, 0, stream>>>(x, P, sorted, n);
        if (full) {
            cvn_main2<<<NB, 1024, 0, stream>>>(sorted, S, V16, V32, V64, V128,
                                               tmp, rank, n);
            cvn_permute<<<grid256, 256, 0, stream>>>(tmp, rank, out, n);
        } else {
            cvn_main<<<nblocks, 256, 0, stream>>>(sorted, V16, V32, V64, V128,
                                                  out, n, nblocks);
        }
    } else {
        cvn_direct<<<grid256, 256, 0, stream>>>(x, V16, V32, V64, V128, out, n);
    }
}

// Round 7
// 252.068 us; speedup vs baseline: 1.4986x; 1.4986x over previous
//
#include <hip/hip_runtime.h>

// CompositeValueNoise R7: 512-bucket global counting sort; main kernel
// fine-sorts each coarse bucket's points into 8 sub-cells in LDS, then for
// each sub-cell stages the 4 grid slices (9^3+5^3+3^3+2^3 float4 = 14 KB)
// into LDS and evaluates with LDS-only corner reads. No global gathers in
// the hot loop -> L2 stays clean -> tmp window writes coalesce into full
// lines. rank[i] written coalesced in scatter; permute epilogue unchanged.

#define NB 512                 // 8^3 coarse buckets
#define PTS_PER_BLK 4096
#define CHUNK 32
#define SC_THREADS 1024
#define SC_PPT (PTS_PER_BLK / SC_THREADS)
#define H_THREADS 256
#define H_PPT (PTS_PER_BLK / H_THREADS)
#define TILE 4608              // mean seg 3906, sd ~62 -> +11 sigma

__device__ __forceinline__ int bucket_of(float px, float py, float pz) {
    int ix = min(max((int)(px * 8.0f), 0), 7);
    int iy = min(max((int)(py * 8.0f), 0), 7);
    int iz = min(max((int)(pz * 8.0f), 0), 7);
    return (ix * 8 + iy) * 8 + iz;
}

__global__ void __launch_bounds__(H_THREADS)
cvn_hist(const float* __restrict__ x, int* __restrict__ P, int n) {
    __shared__ int cnt[NB];
    int t = threadIdx.x;
    for (int q = t; q < NB; q += H_THREADS) cnt[q] = 0;
    __syncthreads();
    int base = blockIdx.x * PTS_PER_BLK;
    for (int k = 0; k < H_PPT; ++k) {
        int i = base + k * H_THREADS + t;
        if (i < n)
            atomicAdd(&cnt[bucket_of(x[3 * i], x[3 * i + 1], x[3 * i + 2])], 1);
    }
    __syncthreads();
    int* Pb = P + (size_t)blockIdx.x * NB;
    for (int q = t; q < NB; q += H_THREADS) Pb[q] = cnt[q];
}

__global__ void __launch_bounds__(256)
cvn_scan_a(const int* __restrict__ P, int* __restrict__ S, int nblk) {
    int q = blockIdx.x * 256 + threadIdx.x;
    int c = blockIdx.y;
    int b0 = c * CHUNK, b1 = min(b0 + CHUNK, nblk);
    int s = 0;
    for (int b = b0; b < b1; ++b) s += P[(size_t)b * NB + q];
    S[(size_t)c * NB + q] = s;
}

// After: S[c][q] = Texcl[q] + exclusive chunk prefix; S[0][q] = bucket base.
__global__ void __launch_bounds__(NB)
cvn_scan_b(int* __restrict__ S, int nch) {
    __shared__ int part[NB];
    int t = threadIdx.x;
    int acc = 0;
    for (int c = 0; c < nch; ++c) {
        int v = S[(size_t)c * NB + t];
        S[(size_t)c * NB + t] = acc;
        acc += v;
    }
    part[t] = acc;
    __syncthreads();
    for (int off = 1; off < NB; off <<= 1) {
        int v = (t >= off) ? part[t - off] : 0;
        __syncthreads();
        if (t >= off) part[t] += v;
        __syncthreads();
    }
    int texcl = (t == 0) ? 0 : part[t - 1];
    for (int c = 0; c < nch; ++c) S[(size_t)c * NB + t] += texcl;
}

__global__ void __launch_bounds__(256)
cvn_scan_c(int* __restrict__ P, const int* __restrict__ S, int nblk) {
    int q = blockIdx.x * 256 + threadIdx.x;
    int c = blockIdx.y;
    int b0 = c * CHUNK, b1 = min(b0 + CHUNK, nblk);
    int run = S[(size_t)c * NB + q];
    for (int b = b0; b < b1; ++b) {
        int v = P[(size_t)b * NB + q];
        P[(size_t)b * NB + q] = run;
        run += v;
    }
}

__global__ void __launch_bounds__(SC_THREADS)
cvn_scatter(const float* __restrict__ x, const int* __restrict__ P,
            float4* __restrict__ sorted, int* __restrict__ rank,
            int n, int write_rank) {
    __shared__ int cnt[NB];
    __shared__ int place[NB];
    __shared__ int Pb[NB];
    __shared__ int sc[NB];
    __shared__ float4 payload[PTS_PER_BLK];
    __shared__ unsigned short bkt[PTS_PER_BLK];
    int t = threadIdx.x, b = blockIdx.x;
    int base = b * PTS_PER_BLK;
    if (t < NB) {
        cnt[t] = 0; place[t] = 0;
        Pb[t] = P[(size_t)b * NB + t];
    }
    __syncthreads();

    float px[SC_PPT], py[SC_PPT], pz[SC_PPT];
    int qq[SC_PPT];
    #pragma unroll
    for (int k = 0; k < SC_PPT; ++k) {
        int i = base + k * SC_THREADS + t;
        if (i < n) {
            px[k] = x[3 * i]; py[k] = x[3 * i + 1]; pz[k] = x[3 * i + 2];
            qq[k] = bucket_of(px[k], py[k], pz[k]);
            atomicAdd(&cnt[qq[k]], 1);
        } else qq[k] = -1;
    }
    __syncthreads();

    if (t < NB) sc[t] = cnt[t];
    __syncthreads();
    for (int off = 1; off < NB; off <<= 1) {
        int v = (t < NB && t >= off) ? sc[t - off] : 0;
        __syncthreads();
        if (t < NB && t >= off) sc[t] += v;
        __syncthreads();
    }
    if (t < NB) cnt[t] = (t == 0) ? 0 : sc[t - 1];
    __syncthreads();

    #pragma unroll
    for (int k = 0; k < SC_PPT; ++k) {
        if (qq[k] >= 0) {
            int q = qq[k];
            int lp = atomicAdd(&place[q], 1);
            int slot = cnt[q] + lp;
            int i = base + k * SC_THREADS + t;
            payload[slot] = make_float4(px[k], py[k], pz[k], __int_as_float(i));
            bkt[slot] = (unsigned short)q;
            if (write_rank) rank[i] = Pb[q] + lp;   // coalesced in i
        }
    }
    __syncthreads();

    int total = min(n - base, PTS_PER_BLK);
    #pragma unroll
    for (int k = 0; k < SC_PPT; ++k) {
        int j = k * SC_THREADS + t;
        if (j < total) {
            int q = bkt[j];
            sorted[Pb[q] + (j - cnt[q])] = payload[j];
        }
    }
}

__device__ __forceinline__ float4 lerp4(float4 a, float4 b, float w) {
    return make_float4(a.x + w * (b.x - a.x),
                       a.y + w * (b.y - a.y),
                       a.z + w * (b.z - a.z),
                       a.w + w * (b.w - a.w));
}

template <int RES>
__device__ __forceinline__ float4 level_val(const float4* __restrict__ V,
                                            float px, float py, float pz) {
    constexpr int S = RES + 1;
    float xs = fmodf(px * (float)RES, (float)RES);
    float ys = fmodf(py * (float)RES, (float)RES);
    float zs = fmodf(pz * (float)RES, (float)RES);
    float fx = floorf(xs), fy = floorf(ys), fz = floorf(zs);
    float tx = xs - fx, ty = ys - fy, tz = zs - fz;
    int ix = (int)fx, iy = (int)fy, iz = (int)fz;

    float wx = (3.0f - 2.0f * tx) * tx * tx;
    float wy = (3.0f - 2.0f * ty) * ty * ty;
    float wz = (3.0f - 2.0f * tz) * tz * tz;

    int base = (ix * S + iy) * S + iz;
    const float4* p0 = V + base;
    const float4* p1 = p0 + S * S;

    float4 c000 = p0[0];
    float4 c001 = p0[1];
    float4 c010 = p0[S];
    float4 c011 = p0[S + 1];
    float4 c100 = p1[0];
    float4 c101 = p1[1];
    float4 c110 = p1[S];
    float4 c111 = p1[S + 1];

    float4 m00 = lerp4(c000, c100, wx);
    float4 m01 = lerp4(c001, c101, wx);
    float4 m10 = lerp4(c010, c110, wx);
    float4 m11 = lerp4(c011, c111, wx);
    float4 n0  = lerp4(m00, m10, wy);
    float4 n1  = lerp4(m01, m11, wy);
    return lerp4(n0, n1, wz);
}

__device__ __forceinline__ float4 composite(const float4* __restrict__ V16,
                                            const float4* __restrict__ V32,
                                            const float4* __restrict__ V64,
                                            const float4* __restrict__ V128,
                                            float px, float py, float pz) {
    float4 acc = level_val<16>(V16, px, py, pz);
    float4 v;
    v = level_val<32>(V32, px, py, pz);
    acc.x += 0.5f * v.x; acc.y += 0.5f * v.y; acc.z += 0.5f * v.z; acc.w += 0.5f * v.w;
    v = level_val<64>(V64, px, py, pz);
    acc.x += 0.25f * v.x; acc.y += 0.25f * v.y; acc.z += 0.25f * v.z; acc.w += 0.25f * v.w;
    v = level_val<128>(V128, px, py, pz);
    acc.x += 0.125f * v.x; acc.y += 0.125f * v.y; acc.z += 0.125f * v.z; acc.w += 0.125f * v.w;
    return acc;
}

// Trilinear interp from an LDS slice of (R+1)^3 float4 nodes covering a
// 1/16 fine cell. R = nodes-per-fine-cell for the level (1,2,4,8).
template <int R>
__device__ __forceinline__ float4 lds_interp(const float4* s,
                                             float px, float py, float pz,
                                             int fx, int fy, int fz) {
    constexpr int DIM = R + 1;
    float xs = px * (float)(16 * R);
    float ys = py * (float)(16 * R);
    float zs = pz * (float)(16 * R);
    int ixg = (int)xs, iyg = (int)ys, izg = (int)zs;
    float tx = xs - (float)ixg, ty = ys - (float)iyg, tz = zs - (float)izg;
    int lx = min(max(ixg - fx * R, 0), R - 1);
    int ly = min(max(iyg - fy * R, 0), R - 1);
    int lz = min(max(izg - fz * R, 0), R - 1);

    float wx = (3.0f - 2.0f * tx) * tx * tx;
    float wy = (3.0f - 2.0f * ty) * ty * ty;
    float wz = (3.0f - 2.0f * tz) * tz * tz;

    const float4* p0 = s + (lx * DIM + ly) * DIM + lz;
    const float4* p1 = p0 + DIM * DIM;
    float4 c000 = p0[0],   c001 = p0[1];
    float4 c010 = p0[DIM], c011 = p0[DIM + 1];
    float4 c100 = p1[0],   c101 = p1[1];
    float4 c110 = p1[DIM], c111 = p1[DIM + 1];

    float4 m00 = lerp4(c000, c100, wx);
    float4 m01 = lerp4(c001, c101, wx);
    float4 m10 = lerp4(c010, c110, wx);
    float4 m11 = lerp4(c011, c111, wx);
    float4 n0  = lerp4(m00, m10, wy);
    float4 n1  = lerp4(m01, m11, wy);
    return lerp4(n0, n1, wz);
}

// One WG per coarse bucket. Fine-sort into 8 sub-cells; per sub-cell stage
// grid slices to LDS and evaluate with LDS-only corner reads. tmp written
// at the point's coarse slot (matches rank from scatter).
__global__ void __launch_bounds__(1024)
cvn_main3(const float4* __restrict__ sorted, const int* __restrict__ Tbase,
          const float4* __restrict__ V16, const float4* __restrict__ V32,
          const float4* __restrict__ V64, const float4* __restrict__ V128,
          float4* __restrict__ tmp, int n) {
    __shared__ float4 pts[TILE];             // 73728 B
    __shared__ unsigned char keys[TILE];     //  4608 B
    __shared__ unsigned short perm[TILE];    //  9216 B
    __shared__ int hcnt[8], hstart[9], cursor[8];
    __shared__ float4 s128[9 * 9 * 9];       // 11664 B
    __shared__ float4 s64[5 * 5 * 5];        //  2000 B
    __shared__ float4 s32[3 * 3 * 3];        //   432 B
    __shared__ float4 s16[2 * 2 * 2];        //   128 B
    int t = threadIdx.x, b = blockIdx.x;

    // XCD-compact bucket mapping (b&7 -> octant; g x-slowest).
    int ox = b & 1, oy = (b >> 1) & 1, oz = (b >> 2) & 1;
    int g  = b >> 3;
    int lx = g >> 4, ly = (g >> 2) & 3, lz = g & 3;
    int cix = ox * 4 + lx, ciy = oy * 4 + ly, ciz = oz * 4 + lz;
    int q  = (cix * 8 + ciy) * 8 + ciz;

    int base = Tbase[q];
    int end  = (q == NB - 1) ? n : Tbase[q + 1];
    int len  = end - base;
    int lenT = min(len, TILE);

    if (t < 8) { hcnt[t] = 0; }
    __syncthreads();

    // Load segment; 3-bit sub-cell key (which half of the coarse cell).
    for (int p = t; p < lenT; p += 1024) {
        float4 pt = sorted[base + p];
        pts[p] = pt;
        int sx = ((int)(pt.x * 16.0f)) & 1;
        int sy = ((int)(pt.y * 16.0f)) & 1;
        int sz = ((int)(pt.z * 16.0f)) & 1;
        int key = sx * 4 + sy * 2 + sz;
        keys[p] = (unsigned char)key;
        atomicAdd(&hcnt[key], 1);
    }
    __syncthreads();

    if (t == 0) {
        int s = 0;
        for (int k = 0; k < 8; ++k) { hstart[k] = s; cursor[k] = s; s += hcnt[k]; }
        hstart[8] = s;
    }
    __syncthreads();

    for (int p = t; p < lenT; p += 1024) {
        int slot = atomicAdd(&cursor[keys[p]], 1);
        perm[slot] = (unsigned short)p;
    }
    __syncthreads();

    for (int s = 0; s < 8; ++s) {
        // Fine cell coords of this sub-cell.
        int fx = cix * 2 + ((s >> 2) & 1);
        int fy = ciy * 2 + ((s >> 1) & 1);
        int fz = ciz * 2 + (s & 1);

        // Stage grid slices (889 float4 total).
        if (t < 729) {
            int a = t / 81, bb = (t / 9) % 9, c = t % 9;
            s128[t] = V128[((size_t)(fx * 8 + a) * 129 + (fy * 8 + bb)) * 129
                           + (fz * 8 + c)];
        } else if (t < 729 + 125) {
            int u = t - 729;
            int a = u / 25, bb = (u / 5) % 5, c = u % 5;
            s64[u] = V64[((size_t)(fx * 4 + a) * 65 + (fy * 4 + bb)) * 65
                         + (fz * 4 + c)];
        } else if (t < 729 + 125 + 27) {
            int u = t - 729 - 125;
            int a = u / 9, bb = (u / 3) % 3, c = u % 3;
            s32[u] = V32[((size_t)(fx * 2 + a) * 33 + (fy * 2 + bb)) * 33
                         + (fz * 2 + c)];
        } else if (t < 729 + 125 + 27 + 8) {
            int u = t - 729 - 125 - 27;
            int a = u / 4, bb = (u / 2) % 2, c = u % 2;
            s16[u] = V16[((size_t)(fx + a) * 17 + (fy + bb)) * 17 + (fz + c)];
        }
        __syncthreads();

        int p0 = hstart[s], p1 = hstart[s + 1];
        for (int p = p0 + t; p < p1; p += 1024) {
            int j = perm[p];
            float4 pt = pts[j];
            float4 acc = lds_interp<1>(s16, pt.x, pt.y, pt.z, fx, fy, fz);
            float4 v;
            v = lds_interp<2>(s32, pt.x, pt.y, pt.z, fx, fy, fz);
            acc.x += 0.5f * v.x; acc.y += 0.5f * v.y;
            acc.z += 0.5f * v.z; acc.w += 0.5f * v.w;
            v = lds_interp<4>(s64, pt.x, pt.y, pt.z, fx, fy, fz);
            acc.x += 0.25f * v.x; acc.y += 0.25f * v.y;
            acc.z += 0.25f * v.z; acc.w += 0.25f * v.w;
            v = lds_interp<8>(s128, pt.x, pt.y, pt.z, fx, fy, fz);
            acc.x += 0.125f * v.x; acc.y += 0.125f * v.y;
            acc.z += 0.125f * v.z; acc.w += 0.125f * v.w;
            tmp[base + j] = acc;
        }
        __syncthreads();
    }

    // Overflow tail (~never): global path.
    for (int p = lenT + t; p < len; p += 1024) {
        float4 pt = sorted[base + p];
        tmp[base + p] = composite(V16, V32, V64, V128, pt.x, pt.y, pt.z);
    }
}

// Mid-tier fallback: coarse-sorted order, scattered out write.
__global__ void __launch_bounds__(256)
cvn_main(const float4* __restrict__ sorted,
         const float4* __restrict__ V16, const float4* __restrict__ V32,
         const float4* __restrict__ V64, const float4* __restrict__ V128,
         float4* __restrict__ outbuf, int n, int nblocks) {
    int nb8 = nblocks >> 3;
    int c = (blockIdx.x & 7) * nb8 + (blockIdx.x >> 3);
    int j = c * 256 + (int)threadIdx.x;
    if (j >= n) return;
    float4 p = sorted[j];
    outbuf[__float_as_int(p.w)] = composite(V16, V32, V64, V128, p.x, p.y, p.z);
}

__global__ void __launch_bounds__(256)
cvn_permute(const float4* __restrict__ tmp, const int* __restrict__ rank,
            float4* __restrict__ out, int n) {
    int i = blockIdx.x * 256 + (int)threadIdx.x;
    if (i >= n) return;
    out[i] = tmp[rank[i]];
}

__global__ void __launch_bounds__(256)
cvn_direct(const float* __restrict__ x,
           const float4* __restrict__ V16, const float4* __restrict__ V32,
           const float4* __restrict__ V64, const float4* __restrict__ V128,
           float4* __restrict__ out, int n) {
    int i = blockIdx.x * blockDim.x + threadIdx.x;
    if (i >= n) return;
    out[i] = composite(V16, V32, V64, V128, x[3 * i], x[3 * i + 1], x[3 * i + 2]);
}

extern "C" void kernel_launch(void* const* d_in, const int* in_sizes, int n_in,
                              void* d_out, int out_size, void* d_ws, size_t ws_size,
                              hipStream_t stream) {
    const float*  x    = (const float*)d_in[0];
    const float4* V16  = (const float4*)d_in[1];
    const float4* V32  = (const float4*)d_in[2];
    const float4* V64  = (const float4*)d_in[3];
    const float4* V128 = (const float4*)d_in[4];
    float4* out = (float4*)d_out;

    int n = in_sizes[0] / 3;
    int nblk = (n + PTS_PER_BLK - 1) / PTS_PER_BLK;
    int nch  = (nblk + CHUNK - 1) / CHUNK;

    auto align256 = [](size_t v) { return (v + 255) & ~(size_t)255; };
    size_t offP      = 0;
    size_t offS      = align256(offP + (size_t)nblk * NB * sizeof(int));
    size_t offSorted = align256(offS + (size_t)nch * NB * sizeof(int));
    size_t offRank   = align256(offSorted + (size_t)n * sizeof(float4));
    size_t offTmp    = align256(offRank + (size_t)n * sizeof(int));
    size_t needFull  = offTmp + (size_t)n * sizeof(float4);
    size_t needMid   = offRank;

    int grid256 = (n + 255) / 256;
    int nblocks = ((grid256 + 7) / 8) * 8;

    if (ws_size >= needMid) {
        int*    P      = (int*)((char*)d_ws + offP);
        int*    S      = (int*)((char*)d_ws + offS);
        float4* sorted = (float4*)((char*)d_ws + offSorted);
        bool full = (ws_size >= needFull);
        int*    rank = full ? (int*)((char*)d_ws + offRank) : nullptr;
        float4* tmp  = full ? (float4*)((char*)d_ws + offTmp) : nullptr;

        cvn_hist<<<nblk, H_THREADS, 0, stream>>>(x, P, n);
        cvn_scan_a<<<dim3(NB / 256, nch), 256, 0, stream>>>(P, S, nblk);
        cvn_scan_b<<<1, NB, 0, stream>>>(S, nch);
        cvn_scan_c<<<dim3(NB / 256, nch), 256, 0, stream>>>(P, S, nblk);
        cvn_scatter<<<nblk, SC_THREADS, 0, stream>>>(x, P, sorted, rank, n,
                                                     full ? 1 : 0);
        if (full) {
            cvn_main3<<<NB, 1024, 0, stream>>>(sorted, S, V16, V32, V64, V128,
                                               tmp, n);
            cvn_permute<<<grid256, 256, 0, stream>>>(tmp, rank, out, n);
        } else {
            cvn_main<<<nblocks, 256, 0, stream>>>(sorted, V16, V32, V64, V128,
                                                  out, n, nblocks);
        }
    } else {
        cvn_direct<<<grid256, 256, 0, stream>>>(x, V16, V32, V64, V128, out, n);
    }
}

// Round 8
// 239.852 us; speedup vs baseline: 1.5749x; 1.0509x over previous
//
#include <hip/hip_runtime.h>

// CompositeValueNoise R8: 1024-bucket (16x8x8) counting sort; main kernel
// fine-sorts each bucket's pts into 4 sub-cells (y/z halves), stages per-
// fine-cell grid slices (889 float4 = 14 KB) to LDS, evaluates LDS-only,
// stores results back into the LDS pts array, then streams tmp[] coalesced.
// ~58 KB LDS -> 2 blocks/CU (sync overlap). rank written coalesced in
// scatter; permute epilogue gathers tmp[rank[i]] -> out[i].

#define NB 1024                // 16 x 8 x 8 buckets
#define PTS_PER_BLK 4096
#define CHUNK 32
#define SC_THREADS 1024
#define SC_PPT (PTS_PER_BLK / SC_THREADS)
#define H_THREADS 256
#define H_PPT (PTS_PER_BLK / H_THREADS)
#define TILE 2432              // mean seg 1953, sd ~44 -> +10.8 sigma
#define MT 1024                // main kernel threads

__device__ __forceinline__ int bucket_of(float px, float py, float pz) {
    int ix = min(max((int)(px * 16.0f), 0), 15);
    int iy = min(max((int)(py * 8.0f), 0), 7);
    int iz = min(max((int)(pz * 8.0f), 0), 7);
    return (ix * 8 + iy) * 8 + iz;
}

__global__ void __launch_bounds__(H_THREADS)
cvn_hist(const float* __restrict__ x, int* __restrict__ P, int n) {
    __shared__ int cnt[NB];
    int t = threadIdx.x;
    for (int q = t; q < NB; q += H_THREADS) cnt[q] = 0;
    __syncthreads();
    int base = blockIdx.x * PTS_PER_BLK;
    for (int k = 0; k < H_PPT; ++k) {
        int i = base + k * H_THREADS + t;
        if (i < n)
            atomicAdd(&cnt[bucket_of(x[3 * i], x[3 * i + 1], x[3 * i + 2])], 1);
    }
    __syncthreads();
    int* Pb = P + (size_t)blockIdx.x * NB;
    for (int q = t; q < NB; q += H_THREADS) Pb[q] = cnt[q];
}

__global__ void __launch_bounds__(256)
cvn_scan_a(const int* __restrict__ P, int* __restrict__ S, int nblk) {
    int q = blockIdx.x * 256 + threadIdx.x;
    int c = blockIdx.y;
    int b0 = c * CHUNK, b1 = min(b0 + CHUNK, nblk);
    int s = 0;
    for (int b = b0; b < b1; ++b) s += P[(size_t)b * NB + q];
    S[(size_t)c * NB + q] = s;
}

// After: S[c][q] = Texcl[q] + exclusive chunk prefix; S[0][q] = bucket base.
__global__ void __launch_bounds__(NB)
cvn_scan_b(int* __restrict__ S, int nch) {
    __shared__ int part[NB];
    int t = threadIdx.x;
    int acc = 0;
    for (int c = 0; c < nch; ++c) {
        int v = S[(size_t)c * NB + t];
        S[(size_t)c * NB + t] = acc;
        acc += v;
    }
    part[t] = acc;
    __syncthreads();
    for (int off = 1; off < NB; off <<= 1) {
        int v = (t >= off) ? part[t - off] : 0;
        __syncthreads();
        if (t >= off) part[t] += v;
        __syncthreads();
    }
    int texcl = (t == 0) ? 0 : part[t - 1];
    for (int c = 0; c < nch; ++c) S[(size_t)c * NB + t] += texcl;
}

__global__ void __launch_bounds__(256)
cvn_scan_c(int* __restrict__ P, const int* __restrict__ S, int nblk) {
    int q = blockIdx.x * 256 + threadIdx.x;
    int c = blockIdx.y;
    int b0 = c * CHUNK, b1 = min(b0 + CHUNK, nblk);
    int run = S[(size_t)c * NB + q];
    for (int b = b0; b < b1; ++b) {
        int v = P[(size_t)b * NB + q];
        P[(size_t)b * NB + q] = run;
        run += v;
    }
}

__global__ void __launch_bounds__(SC_THREADS)
cvn_scatter(const float* __restrict__ x, const int* __restrict__ P,
            float4* __restrict__ sorted, int* __restrict__ rank,
            int n, int write_rank) {
    __shared__ int cnt[NB];
    __shared__ int place[NB];
    __shared__ int Pb[NB];
    __shared__ int sc[NB];
    __shared__ float4 payload[PTS_PER_BLK];
    __shared__ unsigned short bkt[PTS_PER_BLK];
    int t = threadIdx.x, b = blockIdx.x;
    int base = b * PTS_PER_BLK;
    cnt[t] = 0; place[t] = 0;
    Pb[t] = P[(size_t)b * NB + t];
    __syncthreads();

    float px[SC_PPT], py[SC_PPT], pz[SC_PPT];
    int qq[SC_PPT];
    #pragma unroll
    for (int k = 0; k < SC_PPT; ++k) {
        int i = base + k * SC_THREADS + t;
        if (i < n) {
            px[k] = x[3 * i]; py[k] = x[3 * i + 1]; pz[k] = x[3 * i + 2];
            qq[k] = bucket_of(px[k], py[k], pz[k]);
            atomicAdd(&cnt[qq[k]], 1);
        } else qq[k] = -1;
    }
    __syncthreads();

    sc[t] = cnt[t];
    __syncthreads();
    for (int off = 1; off < NB; off <<= 1) {
        int v = (t >= off) ? sc[t - off] : 0;
        __syncthreads();
        if (t >= off) sc[t] += v;
        __syncthreads();
    }
    cnt[t] = (t == 0) ? 0 : sc[t - 1];
    __syncthreads();

    #pragma unroll
    for (int k = 0; k < SC_PPT; ++k) {
        if (qq[k] >= 0) {
            int q = qq[k];
            int lp = atomicAdd(&place[q], 1);
            int slot = cnt[q] + lp;
            int i = base + k * SC_THREADS + t;
            payload[slot] = make_float4(px[k], py[k], pz[k], __int_as_float(i));
            bkt[slot] = (unsigned short)q;
            if (write_rank) rank[i] = Pb[q] + lp;   // coalesced in i
        }
    }
    __syncthreads();

    int total = min(n - base, PTS_PER_BLK);
    #pragma unroll
    for (int k = 0; k < SC_PPT; ++k) {
        int j = k * SC_THREADS + t;
        if (j < total) {
            int q = bkt[j];
            sorted[Pb[q] + (j - cnt[q])] = payload[j];
        }
    }
}

__device__ __forceinline__ float4 lerp4(float4 a, float4 b, float w) {
    return make_float4(a.x + w * (b.x - a.x),
                       a.y + w * (b.y - a.y),
                       a.z + w * (b.z - a.z),
                       a.w + w * (b.w - a.w));
}

template <int RES>
__device__ __forceinline__ float4 level_val(const float4* __restrict__ V,
                                            float px, float py, float pz) {
    constexpr int S = RES + 1;
    float xs = fmodf(px * (float)RES, (float)RES);
    float ys = fmodf(py * (float)RES, (float)RES);
    float zs = fmodf(pz * (float)RES, (float)RES);
    float fx = floorf(xs), fy = floorf(ys), fz = floorf(zs);
    float tx = xs - fx, ty = ys - fy, tz = zs - fz;
    int ix = (int)fx, iy = (int)fy, iz = (int)fz;

    float wx = (3.0f - 2.0f * tx) * tx * tx;
    float wy = (3.0f - 2.0f * ty) * ty * ty;
    float wz = (3.0f - 2.0f * tz) * tz * tz;

    int base = (ix * S + iy) * S + iz;
    const float4* p0 = V + base;
    const float4* p1 = p0 + S * S;

    float4 c000 = p0[0];
    float4 c001 = p0[1];
    float4 c010 = p0[S];
    float4 c011 = p0[S + 1];
    float4 c100 = p1[0];
    float4 c101 = p1[1];
    float4 c110 = p1[S];
    float4 c111 = p1[S + 1];

    float4 m00 = lerp4(c000, c100, wx);
    float4 m01 = lerp4(c001, c101, wx);
    float4 m10 = lerp4(c010, c110, wx);
    float4 m11 = lerp4(c011, c111, wx);
    float4 n0  = lerp4(m00, m10, wy);
    float4 n1  = lerp4(m01, m11, wy);
    return lerp4(n0, n1, wz);
}

__device__ __forceinline__ float4 composite(const float4* __restrict__ V16,
                                            const float4* __restrict__ V32,
                                            const float4* __restrict__ V64,
                                            const float4* __restrict__ V128,
                                            float px, float py, float pz) {
    float4 acc = level_val<16>(V16, px, py, pz);
    float4 v;
    v = level_val<32>(V32, px, py, pz);
    acc.x += 0.5f * v.x; acc.y += 0.5f * v.y; acc.z += 0.5f * v.z; acc.w += 0.5f * v.w;
    v = level_val<64>(V64, px, py, pz);
    acc.x += 0.25f * v.x; acc.y += 0.25f * v.y; acc.z += 0.25f * v.z; acc.w += 0.25f * v.w;
    v = level_val<128>(V128, px, py, pz);
    acc.x += 0.125f * v.x; acc.y += 0.125f * v.y; acc.z += 0.125f * v.z; acc.w += 0.125f * v.w;
    return acc;
}

// Trilinear interp from an LDS slice of (R+1)^3 float4 nodes covering one
// 1/16 fine cell. R = nodes-per-fine-cell (1,2,4,8).
template <int R>
__device__ __forceinline__ float4 lds_interp(const float4* s,
                                             float px, float py, float pz,
                                             int fx, int fy, int fz) {
    constexpr int DIM = R + 1;
    float xs = px * (float)(16 * R);
    float ys = py * (float)(16 * R);
    float zs = pz * (float)(16 * R);
    int ixg = (int)xs, iyg = (int)ys, izg = (int)zs;
    float tx = xs - (float)ixg, ty = ys - (float)iyg, tz = zs - (float)izg;
    int lx = min(max(ixg - fx * R, 0), R - 1);
    int ly = min(max(iyg - fy * R, 0), R - 1);
    int lz = min(max(izg - fz * R, 0), R - 1);

    float wx = (3.0f - 2.0f * tx) * tx * tx;
    float wy = (3.0f - 2.0f * ty) * ty * ty;
    float wz = (3.0f - 2.0f * tz) * tz * tz;

    const float4* p0 = s + (lx * DIM + ly) * DIM + lz;
    const float4* p1 = p0 + DIM * DIM;
    float4 c000 = p0[0],   c001 = p0[1];
    float4 c010 = p0[DIM], c011 = p0[DIM + 1];
    float4 c100 = p1[0],   c101 = p1[1];
    float4 c110 = p1[DIM], c111 = p1[DIM + 1];

    float4 m00 = lerp4(c000, c100, wx);
    float4 m01 = lerp4(c001, c101, wx);
    float4 m10 = lerp4(c010, c110, wx);
    float4 m11 = lerp4(c011, c111, wx);
    float4 n0  = lerp4(m00, m10, wy);
    float4 n1  = lerp4(m01, m11, wy);
    return lerp4(n0, n1, wz);
}

// One WG per 1/16x1/8x1/8 bucket. Fine-sort into 4 sub-cells (y/z halves);
// per sub-cell stage grid slices to LDS, evaluate LDS-only, store result
// back into pts[j]; finally stream pts -> tmp coalesced.
__global__ void __launch_bounds__(MT)
cvn_main4(const float4* __restrict__ sorted, const int* __restrict__ Tbase,
          const float4* __restrict__ V16, const float4* __restrict__ V32,
          const float4* __restrict__ V64, const float4* __restrict__ V128,
          float4* __restrict__ tmp, int n) {
    __shared__ float4 pts[TILE];             // 38912 B (points, then results)
    __shared__ unsigned short perm[TILE];    //  4864 B
    __shared__ int bins[4], hstart[5], cursor[4];
    __shared__ float4 s128[9 * 9 * 9];       // 11664 B
    __shared__ float4 s64[5 * 5 * 5];        //  2000 B
    __shared__ float4 s32[3 * 3 * 3];        //   432 B
    __shared__ float4 s16[2 * 2 * 2];        //   128 B
    int t = threadIdx.x, b = blockIdx.x;
    int lane = t & 63;
    unsigned long long lanemask_lt = (lane == 0) ? 0ull : (~0ull >> (64 - lane));

    // XCD-compact mapping: b&7 -> octant of the 16x8x8 bucket space
    // (8x4x4 buckets each); g enumerated x-slowest so the ~64 resident
    // buckets per XCD form a compact region (~2.2 MB V128 slice < 4MB L2).
    int ox = b & 1, oy = (b >> 1) & 1, oz = (b >> 2) & 1;
    int g  = b >> 3;                         // 0..127
    int gx = g >> 4, gy = (g >> 2) & 3, gz = g & 3;
    int ix16 = ox * 8 + gx, iy8 = oy * 4 + gy, iz8 = oz * 4 + gz;
    int q = (ix16 * 8 + iy8) * 8 + iz8;

    int base = Tbase[q];
    int end  = (q == NB - 1) ? n : Tbase[q + 1];
    int len  = end - base;
    int lenT = min(len, TILE);

    if (t < 4) bins[t] = 0;
    __syncthreads();

    // Load + wave-aggregated 4-bin histogram (key = y/z half bits).
    for (int p0 = 0; p0 < lenT; p0 += MT) {
        int p = p0 + t;
        int key = 4;
        if (p < lenT) {
            float4 pt = sorted[base + p];
            pts[p] = pt;
            key = ((((int)(pt.y * 16.0f)) & 1) << 1) | (((int)(pt.z * 16.0f)) & 1);
        }
        unsigned long long m0 = __ballot(key == 0);
        unsigned long long m1 = __ballot(key == 1);
        unsigned long long m2 = __ballot(key == 2);
        unsigned long long m3 = __ballot(key == 3);
        if (lane == 0) {
            if (m0) atomicAdd(&bins[0], (int)__popcll(m0));
            if (m1) atomicAdd(&bins[1], (int)__popcll(m1));
            if (m2) atomicAdd(&bins[2], (int)__popcll(m2));
            if (m3) atomicAdd(&bins[3], (int)__popcll(m3));
        }
    }
    __syncthreads();

    if (t == 0) {
        int s = 0;
        #pragma unroll
        for (int k = 0; k < 4; ++k) { hstart[k] = s; cursor[k] = s; s += bins[k]; }
        hstart[4] = s;
    }
    __syncthreads();

    // Build perm with wave-aggregated cursor bumps.
    for (int p0 = 0; p0 < lenT; p0 += MT) {
        int p = p0 + t;
        int key = 4;
        if (p < lenT) {
            float4 pt = pts[p];
            key = ((((int)(pt.y * 16.0f)) & 1) << 1) | (((int)(pt.z * 16.0f)) & 1);
        }
        unsigned long long m0 = __ballot(key == 0);
        unsigned long long m1 = __ballot(key == 1);
        unsigned long long m2 = __ballot(key == 2);
        unsigned long long m3 = __ballot(key == 3);
        int b0 = 0, b1 = 0, b2 = 0, b3 = 0;
        if (lane == 0) {
            if (m0) b0 = atomicAdd(&cursor[0], (int)__popcll(m0));
            if (m1) b1 = atomicAdd(&cursor[1], (int)__popcll(m1));
            if (m2) b2 = atomicAdd(&cursor[2], (int)__popcll(m2));
            if (m3) b3 = atomicAdd(&cursor[3], (int)__popcll(m3));
        }
        b0 = __shfl(b0, 0); b1 = __shfl(b1, 0);
        b2 = __shfl(b2, 0); b3 = __shfl(b3, 0);
        if (key < 4) {
            int slot;
            if      (key == 0) slot = b0 + (int)__popcll(m0 & lanemask_lt);
            else if (key == 1) slot = b1 + (int)__popcll(m1 & lanemask_lt);
            else if (key == 2) slot = b2 + (int)__popcll(m2 & lanemask_lt);
            else               slot = b3 + (int)__popcll(m3 & lanemask_lt);
            perm[slot] = (unsigned short)p;
        }
    }
    __syncthreads();

    for (int s = 0; s < 4; ++s) {
        int fx = ix16;
        int fy = iy8 * 2 + (s >> 1);
        int fz = iz8 * 2 + (s & 1);

        // Stage grid slices (889 float4 = 14224 B).
        if (t < 729) {
            int a = t / 81, bb = (t / 9) % 9, c = t % 9;
            s128[t] = V128[((size_t)(fx * 8 + a) * 129 + (fy * 8 + bb)) * 129
                           + (fz * 8 + c)];
        } else if (t < 729 + 125) {
            int u = t - 729;
            int a = u / 25, bb = (u / 5) % 5, c = u % 5;
            s64[u] = V64[((size_t)(fx * 4 + a) * 65 + (fy * 4 + bb)) * 65
                         + (fz * 4 + c)];
        } else if (t < 729 + 125 + 27) {
            int u = t - 729 - 125;
            int a = u / 9, bb = (u / 3) % 3, c = u % 3;
            s32[u] = V32[((size_t)(fx * 2 + a) * 33 + (fy * 2 + bb)) * 33
                         + (fz * 2 + c)];
        } else if (t < 729 + 125 + 27 + 8) {
            int u = t - 729 - 125 - 27;
            int a = u / 4, bb = (u / 2) % 2, c = u % 2;
            s16[u] = V16[((size_t)(fx + a) * 17 + (fy + bb)) * 17 + (fz + c)];
        }
        __syncthreads();

        int p0 = hstart[s], p1 = hstart[s + 1];
        for (int p = p0 + t; p < p1; p += MT) {
            int j = perm[p];
            float4 pt = pts[j];
            float4 acc = lds_interp<1>(s16, pt.x, pt.y, pt.z, fx, fy, fz);
            float4 v;
            v = lds_interp<2>(s32, pt.x, pt.y, pt.z, fx, fy, fz);
            acc.x += 0.5f * v.x; acc.y += 0.5f * v.y;
            acc.z += 0.5f * v.z; acc.w += 0.5f * v.w;
            v = lds_interp<4>(s64, pt.x, pt.y, pt.z, fx, fy, fz);
            acc.x += 0.25f * v.x; acc.y += 0.25f * v.y;
            acc.z += 0.25f * v.z; acc.w += 0.25f * v.w;
            v = lds_interp<8>(s128, pt.x, pt.y, pt.z, fx, fy, fz);
            acc.x += 0.125f * v.x; acc.y += 0.125f * v.y;
            acc.z += 0.125f * v.z; acc.w += 0.125f * v.w;
            pts[j] = acc;          // result replaces point (same thread RW)
        }
        __syncthreads();
    }

    // Coalesced result stream: tmp[base+j] = result of coarse slot j.
    for (int p = t; p < lenT; p += MT) tmp[base + p] = pts[p];

    // Overflow tail (~never): global path.
    for (int p = lenT + t; p < len; p += MT) {
        float4 pt = sorted[base + p];
        tmp[base + p] = composite(V16, V32, V64, V128, pt.x, pt.y, pt.z);
    }
}

// Mid-tier fallback: coarse-sorted order, scattered out write.
__global__ void __launch_bounds__(256)
cvn_main(const float4* __restrict__ sorted,
         const float4* __restrict__ V16, const float4* __restrict__ V32,
         const float4* __restrict__ V64, const float4* __restrict__ V128,
         float4* __restrict__ outbuf, int n, int nblocks) {
    int nb8 = nblocks >> 3;
    int c = (blockIdx.x & 7) * nb8 + (blockIdx.x >> 3);
    int j = c * 256 + (int)threadIdx.x;
    if (j >= n) return;
    float4 p = sorted[j];
    outbuf[__float_as_int(p.w)] = composite(V16, V32, V64, V128, p.x, p.y, p.z);
}

__global__ void __launch_bounds__(256)
cvn_permute(const float4* __restrict__ tmp, const int* __restrict__ rank,
            float4* __restrict__ out, int n) {
    int i = blockIdx.x * 256 + (int)threadIdx.x;
    if (i >= n) return;
    out[i] = tmp[rank[i]];
}

__global__ void __launch_bounds__(256)
cvn_direct(const float* __restrict__ x,
           const float4* __restrict__ V16, const float4* __restrict__ V32,
           const float4* __restrict__ V64, const float4* __restrict__ V128,
           float4* __restrict__ out, int n) {
    int i = blockIdx.x * blockDim.x + threadIdx.x;
    if (i >= n) return;
    out[i] = composite(V16, V32, V64, V128, x[3 * i], x[3 * i + 1], x[3 * i + 2]);
}

extern "C" void kernel_launch(void* const* d_in, const int* in_sizes, int n_in,
                              void* d_out, int out_size, void* d_ws, size_t ws_size,
                              hipStream_t stream) {
    const float*  x    = (const float*)d_in[0];
    const float4* V16  = (const float4*)d_in[1];
    const float4* V32  = (const float4*)d_in[2];
    const float4* V64  = (const float4*)d_in[3];
    const float4* V128 = (const float4*)d_in[4];
    float4* out = (float4*)d_out;

    int n = in_sizes[0] / 3;
    int nblk = (n + PTS_PER_BLK - 1) / PTS_PER_BLK;
    int nch  = (nblk + CHUNK - 1) / CHUNK;

    auto align256 = [](size_t v) { return (v + 255) & ~(size_t)255; };
    size_t offP      = 0;
    size_t offS      = align256(offP + (size_t)nblk * NB * sizeof(int));
    size_t offSorted = align256(offS + (size_t)nch * NB * sizeof(int));
    size_t offRank   = align256(offSorted + (size_t)n * sizeof(float4));
    size_t offTmp    = align256(offRank + (size_t)n * sizeof(int));
    size_t needFull  = offTmp + (size_t)n * sizeof(float4);
    size_t needMid   = offRank;

    int grid256 = (n + 255) / 256;
    int nblocks = ((grid256 + 7) / 8) * 8;

    if (ws_size >= needMid) {
        int*    P      = (int*)((char*)d_ws + offP);
        int*    S      = (int*)((char*)d_ws + offS);
        float4* sorted = (float4*)((char*)d_ws + offSorted);
        bool full = (ws_size >= needFull);
        int*    rank = full ? (int*)((char*)d_ws + offRank) : nullptr;
        float4* tmp  = full ? (float4*)((char*)d_ws + offTmp) : nullptr;

        cvn_hist<<<nblk, H_THREADS, 0, stream>>>(x, P, n);
        cvn_scan_a<<<dim3(NB / 256, nch), 256, 0, stream>>>(P, S, nblk);
        cvn_scan_b<<<1, NB, 0, stream>>>(S, nch);
        cvn_scan_c<<<dim3(NB / 256, nch), 256, 0, stream>>>(P, S, nblk);
        cvn_scatter<<<nblk, SC_THREADS, 0, stream>>>(x, P, sorted, rank, n,
                                                     full ? 1 : 0);
        if (full) {
            cvn_main4<<<NB, MT, 0, stream>>>(sorted, S, V16, V32, V64, V128,
                                             tmp, n);
            cvn_permute<<<grid256, 256, 0, stream>>>(tmp, rank, out, n);
        } else {
            cvn_main<<<nblocks, 256, 0, stream>>>(sorted, V16, V32, V64, V128,
                                                  out, n, nblocks);
        }
    } else {
        cvn_direct<<<grid256, 256, 0, stream>>>(x, V16, V32, V64, V128, out, n);
    }
}